// Round 6
// baseline (294.449 us; speedup 1.0000x reference)
//
#include <hip/hip_runtime.h>
#include <hip/hip_fp16.h>

#define ALPHA 0.5f

typedef short short8v __attribute__((ext_vector_type(8)));
typedef float f32x4 __attribute__((ext_vector_type(4)));

__device__ __forceinline__ unsigned short f2bf(float f) {
  union { float f; unsigned u; } v; v.f = f;
  unsigned r = v.u + 0x7FFFu + ((v.u >> 16) & 1u);   // RNE
  return (unsigned short)(r >> 16);
}
__device__ __forceinline__ float bf2f(unsigned short u) {
  union { unsigned u; float f; } v; v.u = ((unsigned)u) << 16;
  return v.f;
}

// ---------------- Wt[n][k] = bf16(W[k][n]) ----------------
__global__ void transpose_w(const float* __restrict__ W, unsigned short* __restrict__ Wt) {
  __shared__ float tile[16][17];
  int kb = blockIdx.x * 16, nb = blockIdx.y * 16;
  tile[threadIdx.y][threadIdx.x] = W[(kb + threadIdx.y) * 256 + nb + threadIdx.x];
  __syncthreads();
  Wt[(nb + threadIdx.y) * 256 + kb + threadIdx.x] = f2bf(tile[threadIdx.x][threadIdx.y]);
}

// ---------------- GEMM: support(bf16, SLICED layout) = input @ W via MFMA ----------------
// Output layout: support[slice][node][32], slice = col>>5. 8 contiguous 3.2MB tables.
__global__ __launch_bounds__(256) void gemm_mfma(
    const float* __restrict__ A, const unsigned short* __restrict__ Wt,
    unsigned short* __restrict__ C, int M) {
  __shared__ char smem[2][24576];
  const int tid = threadIdx.x;
  const int lane = tid & 63;
  const int w = tid >> 6;
  const int wm = w >> 1, wn = w & 1;
  const int row0 = blockIdx.x * 128;

  f32x4 acc[4][8];
  #pragma unroll
  for (int m = 0; m < 4; ++m)
    #pragma unroll
    for (int n = 0; n < 8; ++n) acc[m][n] = (f32x4){0.f, 0.f, 0.f, 0.f};

  const int aR = tid >> 1;
  const int aKs = (tid & 1) * 16;
  const int aRow = (row0 + aR < M) ? (row0 + aR) : (M - 1);
  const float* aP = A + (size_t)aRow * 256 + aKs;
  const int aWrOff = (aR >> 4) * 1024 + (aKs >> 3) * 256 + (aR & 15) * 16;

  int cur = 0;
  {
    float4 av[4];
    #pragma unroll
    for (int j = 0; j < 4; ++j) av[j] = *reinterpret_cast<const float4*>(aP + j * 4);
    #pragma unroll
    for (int i = 0; i < 4; ++i) {
      int s = w * 4 + i;
      const unsigned short* g = Wt + (size_t)(s * 16 + (lane & 15)) * 256 + (lane >> 4) * 8;
      __builtin_amdgcn_global_load_lds(
          (const __attribute__((address_space(1))) void*)g,
          (__attribute__((address_space(3))) void*)(&smem[0][8192 + s * 1024]),
          16, 0, 0);
    }
    unsigned short ab[16];
    #pragma unroll
    for (int j = 0; j < 4; ++j) {
      ab[j * 4 + 0] = f2bf(av[j].x); ab[j * 4 + 1] = f2bf(av[j].y);
      ab[j * 4 + 2] = f2bf(av[j].z); ab[j * 4 + 3] = f2bf(av[j].w);
    }
    *reinterpret_cast<short8v*>(&smem[0][aWrOff])       = *reinterpret_cast<short8v*>(&ab[0]);
    *reinterpret_cast<short8v*>(&smem[0][aWrOff + 256]) = *reinterpret_cast<short8v*>(&ab[8]);
    __syncthreads();
  }

  #pragma unroll
  for (int t = 0; t < 8; ++t) {
    float4 av[4];
    const bool pf = (t < 7);
    if (pf) {
      const int k0 = (t + 1) * 32;
      #pragma unroll
      for (int j = 0; j < 4; ++j) av[j] = *reinterpret_cast<const float4*>(aP + k0 + j * 4);
      #pragma unroll
      for (int i = 0; i < 4; ++i) {
        int s = w * 4 + i;
        const unsigned short* g = Wt + (size_t)(s * 16 + (lane & 15)) * 256 + k0 + (lane >> 4) * 8;
        __builtin_amdgcn_global_load_lds(
            (const __attribute__((address_space(1))) void*)g,
            (__attribute__((address_space(3))) void*)(&smem[cur ^ 1][8192 + s * 1024]),
            16, 0, 0);
      }
    }
    short8v af[4], bfv[8];
    #pragma unroll
    for (int m = 0; m < 4; ++m)
      af[m] = *reinterpret_cast<const short8v*>(&smem[cur][(wm * 4 + m) * 1024 + lane * 16]);
    #pragma unroll
    for (int n = 0; n < 8; ++n)
      bfv[n] = *reinterpret_cast<const short8v*>(&smem[cur][8192 + (wn * 8 + n) * 1024 + lane * 16]);
    #pragma unroll
    for (int m = 0; m < 4; ++m)
      #pragma unroll
      for (int n = 0; n < 8; ++n)
        acc[m][n] = __builtin_amdgcn_mfma_f32_16x16x32_bf16(af[m], bfv[n], acc[m][n], 0, 0, 0);
    if (pf) {
      unsigned short ab[16];
      #pragma unroll
      for (int j = 0; j < 4; ++j) {
        ab[j * 4 + 0] = f2bf(av[j].x); ab[j * 4 + 1] = f2bf(av[j].y);
        ab[j * 4 + 2] = f2bf(av[j].z); ab[j * 4 + 3] = f2bf(av[j].w);
      }
      *reinterpret_cast<short8v*>(&smem[cur ^ 1][aWrOff])       = *reinterpret_cast<short8v*>(&ab[0]);
      *reinterpret_cast<short8v*>(&smem[cur ^ 1][aWrOff + 256]) = *reinterpret_cast<short8v*>(&ab[8]);
    }
    __syncthreads();
    cur ^= 1;
  }

  const size_t N32 = (size_t)M * 32;
  #pragma unroll
  for (int m = 0; m < 4; ++m) {
    #pragma unroll
    for (int n = 0; n < 8; ++n) {
      const int col = wn * 128 + n * 16 + (lane & 15);
      const int slice = col >> 5, cwi = col & 31;
      unsigned short* cb = C + (size_t)slice * N32 + cwi;
      #pragma unroll
      for (int r = 0; r < 4; ++r) {
        const int row = row0 + wm * 64 + m * 16 + (lane >> 4) * 4 + r;
        if (row < M) cb[(size_t)row * 32] = f2bf(acc[m][n][r]);
      }
    }
  }
}

// ---------------- CSR build ----------------
__global__ void histogram_dst(const int* __restrict__ dst, int* __restrict__ deg, int E) {
  int i = blockIdx.x * blockDim.x + threadIdx.x;
  if (i < E) atomicAdd(&deg[dst[i]], 1);
}

__global__ __launch_bounds__(256) void scan_pass1(const int* __restrict__ deg,
                                                  int* __restrict__ excl,
                                                  int* __restrict__ partial, int N) {
  const int tid = threadIdx.x;
  const int base = blockIdx.x * 1024 + tid * 4;
  int4 v = make_int4(0, 0, 0, 0);
  if (base + 3 < N) v = *reinterpret_cast<const int4*>(&deg[base]);
  else {
    if (base + 0 < N) v.x = deg[base + 0];
    if (base + 1 < N) v.y = deg[base + 1];
    if (base + 2 < N) v.z = deg[base + 2];
  }
  const int s = v.x + v.y + v.z + v.w;
  const int lane = tid & 63, wid = tid >> 6;
  int ps = s;
  #pragma unroll
  for (int off = 1; off < 64; off <<= 1) {
    int t = __shfl_up(ps, off, 64);
    if (lane >= off) ps += t;
  }
  __shared__ int wsum[4];
  if (lane == 63) wsum[wid] = ps;
  __syncthreads();
  int woff = 0;
  #pragma unroll
  for (int w2 = 0; w2 < 4; ++w2) woff += (w2 < wid) ? wsum[w2] : 0;
  const int texcl = woff + ps - s;
  int4 e = make_int4(texcl, texcl + v.x, texcl + v.x + v.y, texcl + v.x + v.y + v.z);
  if (base + 3 < N) *reinterpret_cast<int4*>(&excl[base]) = e;
  else {
    if (base + 0 < N) excl[base + 0] = e.x;
    if (base + 1 < N) excl[base + 1] = e.y;
    if (base + 2 < N) excl[base + 2] = e.z;
  }
  if (tid == 255) partial[blockIdx.x] = woff + ps;
}

__global__ __launch_bounds__(256) void scan_pass2(const int* __restrict__ excl,
                                                  const int* __restrict__ partial,
                                                  int* __restrict__ row_ptr,
                                                  int* __restrict__ cursor, int N, int NB) {
  __shared__ int s_off;
  const int tid = threadIdx.x;
  if (tid < 64) {
    int v = (tid < NB && tid < (int)blockIdx.x) ? partial[tid] : 0;
    #pragma unroll
    for (int off = 1; off < 64; off <<= 1) v += __shfl_xor(v, off, 64);
    if (tid == 0) s_off = v;
  }
  __syncthreads();
  const int off = s_off;
  const int base = blockIdx.x * 1024 + tid * 4;
  if (base + 3 < N) {
    int4 v = *reinterpret_cast<const int4*>(&excl[base]);
    v.x += off; v.y += off; v.z += off; v.w += off;
    *reinterpret_cast<int4*>(&row_ptr[base]) = v;
    *reinterpret_cast<int4*>(&cursor[base]) = v;
  } else {
    for (int j = 0; j < 4; ++j)
      if (base + j < N) { int v = excl[base + j] + off; row_ptr[base + j] = v; cursor[base + j] = v; }
  }
}

// edge word: src (17 bits) << 15 | fp16(w*alpha) >> 1 (15 bits; w*alpha in [0,0.5])
__global__ void reindex_edges(const int* __restrict__ src, const int* __restrict__ dst,
                              const float* __restrict__ w, int* __restrict__ cursor,
                              unsigned* __restrict__ edges, int E) {
  int i = blockIdx.x * blockDim.x + threadIdx.x;
  if (i < E) {
    int d = dst[i];
    int slot = atomicAdd(&cursor[d], 1);
    unsigned hb = __half_as_ushort(__float2half(w[i] * ALPHA));
    edges[slot] = ((unsigned)src[i] << 15) | (hb >> 1);
  }
}

__device__ __forceinline__ float unpack_w(unsigned p) {
  return __half2float(__ushort_as_half((unsigned short)((p & 0x7FFFu) << 1)));
}

// ---------------- aggregate: sliced, XCD-affine ----------------
// Grid: ng-groups x 8 slices; slice = blockIdx & 7 (XCD round-robin affinity).
// Block: 4 waves, one node per wave. Lane = (edge parity 0/1) x (32 features).
__global__ __launch_bounds__(256) void aggregate(
    const unsigned short* __restrict__ support,  // [8][N][32] sliced
    const int* __restrict__ row_ptr, const int* __restrict__ deg,
    const unsigned* __restrict__ edges,
    const float* __restrict__ init, float* __restrict__ out, int N) {
  const int slice = blockIdx.x & 7;
  const int node = (blockIdx.x >> 3) * 4 + (threadIdx.x >> 6);
  if (node >= N) return;
  const int lane = threadIdx.x & 63;
  const int f = lane & 31;
  const int par = lane >> 5;
  const unsigned short* sb = support + (size_t)slice * ((size_t)N * 32) + f;
  const int start = row_ptr[node], cnt = deg[node];

  float acc = 0.f;
  int e = 0;
  for (; e + 7 < cnt; e += 8) {  // 8 edges/iter: 4 gathers per lane in flight
    unsigned p0 = edges[start + e + 0 + par];
    unsigned p1 = edges[start + e + 2 + par];
    unsigned p2 = edges[start + e + 4 + par];
    unsigned p3 = edges[start + e + 6 + par];
    unsigned short v0 = sb[(size_t)(p0 >> 15) * 32];
    unsigned short v1 = sb[(size_t)(p1 >> 15) * 32];
    unsigned short v2 = sb[(size_t)(p2 >> 15) * 32];
    unsigned short v3 = sb[(size_t)(p3 >> 15) * 32];
    acc += unpack_w(p0) * bf2f(v0) + unpack_w(p1) * bf2f(v1)
         + unpack_w(p2) * bf2f(v2) + unpack_w(p3) * bf2f(v3);
  }
  for (; e + par < cnt; e += 2) {  // parity-strided remainder covers all leftover edges
    unsigned p = edges[start + e + par];
    acc += unpack_w(p) * bf2f(sb[(size_t)(p >> 15) * 32]);
  }
  acc += __shfl_xor(acc, 32, 64);  // combine the two edge parities
  if (par == 0) {
    const int col = slice * 32 + f;
    float ini = init[(size_t)node * 256 + col];
    out[(size_t)node * 256 + col] = fmaxf(acc + (1.f - ALPHA) * ini, 0.f);
  }
}

extern "C" void kernel_launch(void* const* d_in, const int* in_sizes, int n_in,
                              void* d_out, int out_size, void* d_ws, size_t ws_size,
                              hipStream_t stream) {
  const float* input   = (const float*)d_in[0];
  const int*   adj_src = (const int*)d_in[1];
  const int*   adj_dst = (const int*)d_in[2];
  const float* adj_w   = (const float*)d_in[3];
  const float* init_in = (const float*)d_in[4];
  const float* weight  = (const float*)d_in[5];
  float* out = (float*)d_out;

  const int N = in_sizes[0] / 256;  // 50000
  const int E = in_sizes[1];        // 800000

  char* ws = (char*)d_ws;
  unsigned short* support = (unsigned short*)ws; ws += (size_t)N * 256 * 2;  // sliced [8][N][32]
  unsigned short* Wt      = (unsigned short*)ws; ws += 256 * 256 * 2;
  int* deg     = (int*)ws; ws += (size_t)N * 4;
  int* row_ptr = (int*)ws; ws += (size_t)N * 4;
  int* cursor  = (int*)ws; ws += (size_t)N * 4;
  int* excl    = (int*)ws; ws += (size_t)N * 4;
  int* partial = (int*)ws; ws += 256;
  unsigned* edges = (unsigned*)ws; ws += (size_t)E * 4;

  const int NB = (N + 1023) / 1024;  // 49 (<= 64 required by scan_pass2)

  transpose_w<<<dim3(16, 16), dim3(16, 16), 0, stream>>>(weight, Wt);
  gemm_mfma<<<dim3((N + 127) / 128), 256, 0, stream>>>(input, Wt, support, N);

  hipMemsetAsync(deg, 0, (size_t)N * 4, stream);
  histogram_dst<<<(E + 255) / 256, 256, 0, stream>>>(adj_dst, deg, E);
  scan_pass1<<<NB, 256, 0, stream>>>(deg, excl, partial, N);
  scan_pass2<<<NB, 256, 0, stream>>>(excl, partial, row_ptr, cursor, N, NB);
  reindex_edges<<<(E + 255) / 256, 256, 0, stream>>>(adj_src, adj_dst, adj_w, cursor, edges, E);

  // grid: (node-groups of 4) x 8 slices; slice = blockIdx & 7 -> XCD affinity
  aggregate<<<((N + 3) / 4) * 8, 256, 0, stream>>>(support, row_ptr, deg, edges, init_in, out, N);
}

// Round 7
// 280.822 us; speedup vs baseline: 1.0485x; 1.0485x over previous
//
#include <hip/hip_runtime.h>
#include <hip/hip_fp16.h>

#define ALPHA 0.5f

typedef short short8v __attribute__((ext_vector_type(8)));
typedef float f32x4 __attribute__((ext_vector_type(4)));

__device__ __forceinline__ unsigned short f2bf(float f) {
  union { float f; unsigned u; } v; v.f = f;
  unsigned r = v.u + 0x7FFFu + ((v.u >> 16) & 1u);   // RNE
  return (unsigned short)(r >> 16);
}
__device__ __forceinline__ float bf2f(unsigned short u) {
  union { unsigned u; float f; } v; v.u = ((unsigned)u) << 16;
  return v.f;
}

// ---------------- Wt[n][k] = bf16(W[k][n]) ----------------
__global__ void transpose_w(const float* __restrict__ W, unsigned short* __restrict__ Wt) {
  __shared__ float tile[16][17];
  int kb = blockIdx.x * 16, nb = blockIdx.y * 16;
  tile[threadIdx.y][threadIdx.x] = W[(kb + threadIdx.y) * 256 + nb + threadIdx.x];
  __syncthreads();
  Wt[(nb + threadIdx.y) * 256 + kb + threadIdx.x] = f2bf(tile[threadIdx.x][threadIdx.y]);
}

// ---------------- GEMM: support(bf16, SLICED [8][N][32]) = input @ W via MFMA ----------------
__global__ __launch_bounds__(256) void gemm_mfma(
    const float* __restrict__ A, const unsigned short* __restrict__ Wt,
    unsigned short* __restrict__ C, int M) {
  __shared__ char smem[2][24576];
  const int tid = threadIdx.x;
  const int lane = tid & 63;
  const int w = tid >> 6;
  const int wm = w >> 1, wn = w & 1;
  const int row0 = blockIdx.x * 128;

  f32x4 acc[4][8];
  #pragma unroll
  for (int m = 0; m < 4; ++m)
    #pragma unroll
    for (int n = 0; n < 8; ++n) acc[m][n] = (f32x4){0.f, 0.f, 0.f, 0.f};

  const int aR = tid >> 1;
  const int aKs = (tid & 1) * 16;
  const int aRow = (row0 + aR < M) ? (row0 + aR) : (M - 1);
  const float* aP = A + (size_t)aRow * 256 + aKs;
  const int aWrOff = (aR >> 4) * 1024 + (aKs >> 3) * 256 + (aR & 15) * 16;

  int cur = 0;
  {
    float4 av[4];
    #pragma unroll
    for (int j = 0; j < 4; ++j) av[j] = *reinterpret_cast<const float4*>(aP + j * 4);
    #pragma unroll
    for (int i = 0; i < 4; ++i) {
      int s = w * 4 + i;
      const unsigned short* g = Wt + (size_t)(s * 16 + (lane & 15)) * 256 + (lane >> 4) * 8;
      __builtin_amdgcn_global_load_lds(
          (const __attribute__((address_space(1))) void*)g,
          (__attribute__((address_space(3))) void*)(&smem[0][8192 + s * 1024]),
          16, 0, 0);
    }
    unsigned short ab[16];
    #pragma unroll
    for (int j = 0; j < 4; ++j) {
      ab[j * 4 + 0] = f2bf(av[j].x); ab[j * 4 + 1] = f2bf(av[j].y);
      ab[j * 4 + 2] = f2bf(av[j].z); ab[j * 4 + 3] = f2bf(av[j].w);
    }
    *reinterpret_cast<short8v*>(&smem[0][aWrOff])       = *reinterpret_cast<short8v*>(&ab[0]);
    *reinterpret_cast<short8v*>(&smem[0][aWrOff + 256]) = *reinterpret_cast<short8v*>(&ab[8]);
    __syncthreads();
  }

  #pragma unroll
  for (int t = 0; t < 8; ++t) {
    float4 av[4];
    const bool pf = (t < 7);
    if (pf) {
      const int k0 = (t + 1) * 32;
      #pragma unroll
      for (int j = 0; j < 4; ++j) av[j] = *reinterpret_cast<const float4*>(aP + k0 + j * 4);
      #pragma unroll
      for (int i = 0; i < 4; ++i) {
        int s = w * 4 + i;
        const unsigned short* g = Wt + (size_t)(s * 16 + (lane & 15)) * 256 + k0 + (lane >> 4) * 8;
        __builtin_amdgcn_global_load_lds(
            (const __attribute__((address_space(1))) void*)g,
            (__attribute__((address_space(3))) void*)(&smem[cur ^ 1][8192 + s * 1024]),
            16, 0, 0);
      }
    }
    short8v af[4], bfv[8];
    #pragma unroll
    for (int m = 0; m < 4; ++m)
      af[m] = *reinterpret_cast<const short8v*>(&smem[cur][(wm * 4 + m) * 1024 + lane * 16]);
    #pragma unroll
    for (int n = 0; n < 8; ++n)
      bfv[n] = *reinterpret_cast<const short8v*>(&smem[cur][8192 + (wn * 8 + n) * 1024 + lane * 16]);
    #pragma unroll
    for (int m = 0; m < 4; ++m)
      #pragma unroll
      for (int n = 0; n < 8; ++n)
        acc[m][n] = __builtin_amdgcn_mfma_f32_16x16x32_bf16(af[m], bfv[n], acc[m][n], 0, 0, 0);
    if (pf) {
      unsigned short ab[16];
      #pragma unroll
      for (int j = 0; j < 4; ++j) {
        ab[j * 4 + 0] = f2bf(av[j].x); ab[j * 4 + 1] = f2bf(av[j].y);
        ab[j * 4 + 2] = f2bf(av[j].z); ab[j * 4 + 3] = f2bf(av[j].w);
      }
      *reinterpret_cast<short8v*>(&smem[cur ^ 1][aWrOff])       = *reinterpret_cast<short8v*>(&ab[0]);
      *reinterpret_cast<short8v*>(&smem[cur ^ 1][aWrOff + 256]) = *reinterpret_cast<short8v*>(&ab[8]);
    }
    __syncthreads();
    cur ^= 1;
  }

  const size_t N32 = (size_t)M * 32;
  #pragma unroll
  for (int m = 0; m < 4; ++m) {
    #pragma unroll
    for (int n = 0; n < 8; ++n) {
      const int col = wn * 128 + n * 16 + (lane & 15);
      const int slice = col >> 5, cwi = col & 31;
      unsigned short* cb = C + (size_t)slice * N32 + cwi;
      #pragma unroll
      for (int r = 0; r < 4; ++r) {
        const int row = row0 + wm * 64 + m * 16 + (lane >> 4) * 4 + r;
        if (row < M) cb[(size_t)row * 32] = f2bf(acc[m][n][r]);
      }
    }
  }
}

// ---------------- CSR build ----------------
__global__ void histogram_dst(const int* __restrict__ dst, int* __restrict__ deg, int E) {
  int i = blockIdx.x * blockDim.x + threadIdx.x;
  if (i < E) atomicAdd(&deg[dst[i]], 1);
}

__global__ __launch_bounds__(256) void scan_pass1(const int* __restrict__ deg,
                                                  int* __restrict__ excl,
                                                  int* __restrict__ partial, int N) {
  const int tid = threadIdx.x;
  const int base = blockIdx.x * 1024 + tid * 4;
  int4 v = make_int4(0, 0, 0, 0);
  if (base + 3 < N) v = *reinterpret_cast<const int4*>(&deg[base]);
  else {
    if (base + 0 < N) v.x = deg[base + 0];
    if (base + 1 < N) v.y = deg[base + 1];
    if (base + 2 < N) v.z = deg[base + 2];
  }
  const int s = v.x + v.y + v.z + v.w;
  const int lane = tid & 63, wid = tid >> 6;
  int ps = s;
  #pragma unroll
  for (int off = 1; off < 64; off <<= 1) {
    int t = __shfl_up(ps, off, 64);
    if (lane >= off) ps += t;
  }
  __shared__ int wsum[4];
  if (lane == 63) wsum[wid] = ps;
  __syncthreads();
  int woff = 0;
  #pragma unroll
  for (int w2 = 0; w2 < 4; ++w2) woff += (w2 < wid) ? wsum[w2] : 0;
  const int texcl = woff + ps - s;
  int4 e = make_int4(texcl, texcl + v.x, texcl + v.x + v.y, texcl + v.x + v.y + v.z);
  if (base + 3 < N) *reinterpret_cast<int4*>(&excl[base]) = e;
  else {
    if (base + 0 < N) excl[base + 0] = e.x;
    if (base + 1 < N) excl[base + 1] = e.y;
    if (base + 2 < N) excl[base + 2] = e.z;
  }
  if (tid == 255) partial[blockIdx.x] = woff + ps;
}

__global__ __launch_bounds__(256) void scan_pass2(const int* __restrict__ excl,
                                                  const int* __restrict__ partial,
                                                  int* __restrict__ row_ptr,
                                                  int* __restrict__ cursor, int N, int NB) {
  __shared__ int s_off;
  const int tid = threadIdx.x;
  if (tid < 64) {
    int v = (tid < NB && tid < (int)blockIdx.x) ? partial[tid] : 0;
    #pragma unroll
    for (int off = 1; off < 64; off <<= 1) v += __shfl_xor(v, off, 64);
    if (tid == 0) s_off = v;
  }
  __syncthreads();
  const int off = s_off;
  const int base = blockIdx.x * 1024 + tid * 4;
  if (base + 3 < N) {
    int4 v = *reinterpret_cast<const int4*>(&excl[base]);
    v.x += off; v.y += off; v.z += off; v.w += off;
    *reinterpret_cast<int4*>(&row_ptr[base]) = v;
    *reinterpret_cast<int4*>(&cursor[base]) = v;
  } else {
    for (int j = 0; j < 4; ++j)
      if (base + j < N) { int v = excl[base + j] + off; row_ptr[base + j] = v; cursor[base + j] = v; }
  }
}

// edge word: src (17 bits) << 15 | fp16(w*alpha) >> 1 (15 bits; w*alpha in [0,0.5])
__global__ void reindex_edges(const int* __restrict__ src, const int* __restrict__ dst,
                              const float* __restrict__ w, int* __restrict__ cursor,
                              unsigned* __restrict__ edges, int E) {
  int i = blockIdx.x * blockDim.x + threadIdx.x;
  if (i < E) {
    int d = dst[i];
    int slot = atomicAdd(&cursor[d], 1);
    unsigned hb = __half_as_ushort(__float2half(w[i] * ALPHA));
    edges[slot] = ((unsigned)src[i] << 15) | (hb >> 1);
  }
}

__device__ __forceinline__ float unpack_w(unsigned p) {
  return __half2float(__ushort_as_half((unsigned short)((p & 0x7FFFu) << 1)));
}

// ---------------- aggregate: sliced + XCD-affine, 8 edges per gather instr ----------------
// Grid: node-groups x 8 slices; slice = blockIdx & 7 (XCD round-robin).
// Wave = 1 node; lane = edge-slot (lane>>3, 0..7) x feat-oct (lane&7, 0..7).
// One gather instr = 8 edges x 8 lanes x ushort4(8B) = 512B (one 64B line per edge).
__global__ __launch_bounds__(256) void aggregate(
    const unsigned short* __restrict__ support,  // [8][N][32] sliced
    const int* __restrict__ row_ptr, const int* __restrict__ deg,
    const unsigned* __restrict__ edges,
    const float* __restrict__ init, float* __restrict__ out, int N) {
  const int slice = blockIdx.x & 7;
  const int node = (blockIdx.x >> 3) * 4 + (threadIdx.x >> 6);
  if (node >= N) return;
  const int lane = threadIdx.x & 63;
  const int es = lane >> 3;   // edge slot 0..7
  const int fo = lane & 7;    // feature oct 0..7 (4 bf16 each)
  const unsigned short* sb = support + (size_t)slice * ((size_t)N * 32) + fo * 4;
  const int start = row_ptr[node], cnt = deg[node];

  float4 acc = make_float4(0.f, 0.f, 0.f, 0.f);
  for (int e = 0; e < cnt; e += 8) {
    const int idx = e + es;
    const unsigned p = edges[start + (idx < cnt ? idx : 0)];   // clamp: safe, cnt>0 here
    const float wj = (idx < cnt) ? unpack_w(p) : 0.f;
    ushort4 v = *reinterpret_cast<const ushort4*>(&sb[(size_t)(p >> 15) * 32]);
    acc.x += wj * bf2f(v.x);
    acc.y += wj * bf2f(v.y);
    acc.z += wj * bf2f(v.z);
    acc.w += wj * bf2f(v.w);
  }
  // fold the 8 edge slots (lanes ^8, ^16, ^32)
  #pragma unroll
  for (int m = 8; m < 64; m <<= 1) {
    acc.x += __shfl_xor(acc.x, m, 64);
    acc.y += __shfl_xor(acc.y, m, 64);
    acc.z += __shfl_xor(acc.z, m, 64);
    acc.w += __shfl_xor(acc.w, m, 64);
  }
  if (es == 0) {
    const int col = slice * 32 + fo * 4;
    float4 ini = *reinterpret_cast<const float4*>(&init[(size_t)node * 256 + col]);
    float4 o;
    o.x = fmaxf(acc.x + (1.f - ALPHA) * ini.x, 0.f);
    o.y = fmaxf(acc.y + (1.f - ALPHA) * ini.y, 0.f);
    o.z = fmaxf(acc.z + (1.f - ALPHA) * ini.z, 0.f);
    o.w = fmaxf(acc.w + (1.f - ALPHA) * ini.w, 0.f);
    *reinterpret_cast<float4*>(&out[(size_t)node * 256 + col]) = o;
  }
}

extern "C" void kernel_launch(void* const* d_in, const int* in_sizes, int n_in,
                              void* d_out, int out_size, void* d_ws, size_t ws_size,
                              hipStream_t stream) {
  const float* input   = (const float*)d_in[0];
  const int*   adj_src = (const int*)d_in[1];
  const int*   adj_dst = (const int*)d_in[2];
  const float* adj_w   = (const float*)d_in[3];
  const float* init_in = (const float*)d_in[4];
  const float* weight  = (const float*)d_in[5];
  float* out = (float*)d_out;

  const int N = in_sizes[0] / 256;  // 50000
  const int E = in_sizes[1];        // 800000

  char* ws = (char*)d_ws;
  unsigned short* support = (unsigned short*)ws; ws += (size_t)N * 256 * 2;  // sliced [8][N][32]
  unsigned short* Wt      = (unsigned short*)ws; ws += 256 * 256 * 2;
  int* deg     = (int*)ws; ws += (size_t)N * 4;
  int* row_ptr = (int*)ws; ws += (size_t)N * 4;
  int* cursor  = (int*)ws; ws += (size_t)N * 4;
  int* excl    = (int*)ws; ws += (size_t)N * 4;
  int* partial = (int*)ws; ws += 256;
  unsigned* edges = (unsigned*)ws; ws += (size_t)E * 4;

  const int NB = (N + 1023) / 1024;  // 49 (<= 64 required by scan_pass2)

  transpose_w<<<dim3(16, 16), dim3(16, 16), 0, stream>>>(weight, Wt);
  gemm_mfma<<<dim3((N + 127) / 128), 256, 0, stream>>>(input, Wt, support, N);

  hipMemsetAsync(deg, 0, (size_t)N * 4, stream);
  histogram_dst<<<(E + 255) / 256, 256, 0, stream>>>(adj_dst, deg, E);
  scan_pass1<<<NB, 256, 0, stream>>>(deg, excl, partial, N);
  scan_pass2<<<NB, 256, 0, stream>>>(excl, partial, row_ptr, cursor, N, NB);
  reindex_edges<<<(E + 255) / 256, 256, 0, stream>>>(adj_src, adj_dst, adj_w, cursor, edges, E);

  // grid multiple of 8: slice = blockIdx & 7 -> XCD round-robin affinity
  aggregate<<<((N + 3) / 4) * 8, 256, 0, stream>>>(support, row_ptr, deg, edges, init_in, out, N);
}

// Round 8
// 199.323 us; speedup vs baseline: 1.4772x; 1.4089x over previous
//
#include <hip/hip_runtime.h>
#include <hip/hip_fp16.h>

#define ALPHA 0.5f

typedef short short8v __attribute__((ext_vector_type(8)));
typedef float f32x4 __attribute__((ext_vector_type(4)));

__device__ __forceinline__ unsigned short f2bf(float f) {
  union { float f; unsigned u; } v; v.f = f;
  unsigned r = v.u + 0x7FFFu + ((v.u >> 16) & 1u);   // RNE
  return (unsigned short)(r >> 16);
}
__device__ __forceinline__ float bf2f(unsigned short u) {
  union { unsigned u; float f; } v; v.u = ((unsigned)u) << 16;
  return v.f;
}

// ---------------- Wt[n][k] = bf16(W[k][n]) ----------------
__global__ void transpose_w(const float* __restrict__ W, unsigned short* __restrict__ Wt) {
  __shared__ float tile[16][17];
  int kb = blockIdx.x * 16, nb = blockIdx.y * 16;
  tile[threadIdx.y][threadIdx.x] = W[(kb + threadIdx.y) * 256 + nb + threadIdx.x];
  __syncthreads();
  Wt[(nb + threadIdx.y) * 256 + kb + threadIdx.x] = f2bf(tile[threadIdx.x][threadIdx.y]);
}

// ---------------- Ab = bf16(A): streaming cvt, 8 elems/thread ----------------
__global__ void cvt_input(const float* __restrict__ A, unsigned short* __restrict__ Ab, int n8) {
  int i = blockIdx.x * blockDim.x + threadIdx.x;
  int stride = gridDim.x * blockDim.x;
  for (; i < n8; i += stride) {
    float4 a = *reinterpret_cast<const float4*>(&A[i * 8]);
    float4 b = *reinterpret_cast<const float4*>(&A[i * 8 + 4]);
    unsigned short o[8] = {f2bf(a.x), f2bf(a.y), f2bf(a.z), f2bf(a.w),
                           f2bf(b.x), f2bf(b.y), f2bf(b.z), f2bf(b.w)};
    *reinterpret_cast<short8v*>(&Ab[i * 8]) = *reinterpret_cast<short8v*>(o);
  }
}

// ---------------- GEMM: support(bf16) = Ab @ W via MFMA, all-gload_lds staging ----------------
// 128x256 tile (full N), 4 waves, each wave 64x128 = 4x8 frags of 16x16x32.
// LDS buffer: A 8x1KB @0, B 16x1KB @8192 (frag-order). Double-buffered (48KB).
__global__ __launch_bounds__(256) void gemm_mfma(
    const unsigned short* __restrict__ Ab, const unsigned short* __restrict__ Wt,
    unsigned short* __restrict__ C, int M) {
  __shared__ char smem[2][24576];
  const int tid = threadIdx.x;
  const int lane = tid & 63;
  const int w = tid >> 6;
  const int wm = w >> 1, wn = w & 1;
  const int row0 = blockIdx.x * 128;

  f32x4 acc[4][8];
  #pragma unroll
  for (int m = 0; m < 4; ++m)
    #pragma unroll
    for (int n = 0; n < 8; ++n) acc[m][n] = (f32x4){0.f, 0.f, 0.f, 0.f};

  // per-lane A global rows for this wave's 2 subtiles (clamped at M edge)
  int arow[2];
  #pragma unroll
  for (int i = 0; i < 2; ++i) {
    int r = row0 + (w * 2 + i) * 16 + (lane & 15);
    arow[i] = (r < M) ? r : (M - 1);
  }
  const int kh = (lane >> 4) * 8;  // k-offset within 32-wide K-step

  int cur = 0;
  // prologue: stage K-tile 0 into buf 0
  {
    #pragma unroll
    for (int i = 0; i < 2; ++i) {
      int s = w * 2 + i;
      const unsigned short* g = Ab + (size_t)arow[i] * 256 + kh;
      __builtin_amdgcn_global_load_lds(
          (const __attribute__((address_space(1))) void*)g,
          (__attribute__((address_space(3))) void*)(&smem[0][s * 1024]),
          16, 0, 0);
    }
    #pragma unroll
    for (int i = 0; i < 4; ++i) {
      int s = w * 4 + i;
      const unsigned short* g = Wt + (size_t)(s * 16 + (lane & 15)) * 256 + kh;
      __builtin_amdgcn_global_load_lds(
          (const __attribute__((address_space(1))) void*)g,
          (__attribute__((address_space(3))) void*)(&smem[0][8192 + s * 1024]),
          16, 0, 0);
    }
    __syncthreads();
  }

  #pragma unroll
  for (int t = 0; t < 8; ++t) {
    const bool pf = (t < 7);
    if (pf) {
      const int k0 = (t + 1) * 32;
      #pragma unroll
      for (int i = 0; i < 2; ++i) {
        int s = w * 2 + i;
        const unsigned short* g = Ab + (size_t)arow[i] * 256 + k0 + kh;
        __builtin_amdgcn_global_load_lds(
            (const __attribute__((address_space(1))) void*)g,
            (__attribute__((address_space(3))) void*)(&smem[cur ^ 1][s * 1024]),
            16, 0, 0);
      }
      #pragma unroll
      for (int i = 0; i < 4; ++i) {
        int s = w * 4 + i;
        const unsigned short* g = Wt + (size_t)(s * 16 + (lane & 15)) * 256 + k0 + kh;
        __builtin_amdgcn_global_load_lds(
            (const __attribute__((address_space(1))) void*)g,
            (__attribute__((address_space(3))) void*)(&smem[cur ^ 1][8192 + s * 1024]),
            16, 0, 0);
      }
    }
    short8v af[4], bfv[8];
    #pragma unroll
    for (int m = 0; m < 4; ++m)
      af[m] = *reinterpret_cast<const short8v*>(&smem[cur][(wm * 4 + m) * 1024 + lane * 16]);
    #pragma unroll
    for (int n = 0; n < 8; ++n)
      bfv[n] = *reinterpret_cast<const short8v*>(&smem[cur][8192 + (wn * 8 + n) * 1024 + lane * 16]);
    #pragma unroll
    for (int m = 0; m < 4; ++m)
      #pragma unroll
      for (int n = 0; n < 8; ++n)
        acc[m][n] = __builtin_amdgcn_mfma_f32_16x16x32_bf16(af[m], bfv[n], acc[m][n], 0, 0, 0);
    __syncthreads();
    cur ^= 1;
  }

  #pragma unroll
  for (int m = 0; m < 4; ++m) {
    #pragma unroll
    for (int n = 0; n < 8; ++n) {
      const int col = wn * 128 + n * 16 + (lane & 15);
      #pragma unroll
      for (int r = 0; r < 4; ++r) {
        const int row = row0 + wm * 64 + m * 16 + (lane >> 4) * 4 + r;
        if (row < M) C[(size_t)row * 256 + col] = f2bf(acc[m][n][r]);
      }
    }
  }
}

// ---------------- CSR build ----------------
__global__ void histogram_dst(const int* __restrict__ dst, int* __restrict__ deg, int E) {
  int i = blockIdx.x * blockDim.x + threadIdx.x;
  if (i < E) atomicAdd(&deg[dst[i]], 1);
}

__global__ __launch_bounds__(256) void scan_pass1(const int* __restrict__ deg,
                                                  int* __restrict__ excl,
                                                  int* __restrict__ partial, int N) {
  const int tid = threadIdx.x;
  const int base = blockIdx.x * 1024 + tid * 4;
  int4 v = make_int4(0, 0, 0, 0);
  if (base + 3 < N) v = *reinterpret_cast<const int4*>(&deg[base]);
  else {
    if (base + 0 < N) v.x = deg[base + 0];
    if (base + 1 < N) v.y = deg[base + 1];
    if (base + 2 < N) v.z = deg[base + 2];
  }
  const int s = v.x + v.y + v.z + v.w;
  const int lane = tid & 63, wid = tid >> 6;
  int ps = s;
  #pragma unroll
  for (int off = 1; off < 64; off <<= 1) {
    int t = __shfl_up(ps, off, 64);
    if (lane >= off) ps += t;
  }
  __shared__ int wsum[4];
  if (lane == 63) wsum[wid] = ps;
  __syncthreads();
  int woff = 0;
  #pragma unroll
  for (int w2 = 0; w2 < 4; ++w2) woff += (w2 < wid) ? wsum[w2] : 0;
  const int texcl = woff + ps - s;
  int4 e = make_int4(texcl, texcl + v.x, texcl + v.x + v.y, texcl + v.x + v.y + v.z);
  if (base + 3 < N) *reinterpret_cast<int4*>(&excl[base]) = e;
  else {
    if (base + 0 < N) excl[base + 0] = e.x;
    if (base + 1 < N) excl[base + 1] = e.y;
    if (base + 2 < N) excl[base + 2] = e.z;
  }
  if (tid == 255) partial[blockIdx.x] = woff + ps;
}

__global__ __launch_bounds__(256) void scan_pass2(const int* __restrict__ excl,
                                                  const int* __restrict__ partial,
                                                  int* __restrict__ row_ptr,
                                                  int* __restrict__ cursor, int N, int NB) {
  __shared__ int s_off;
  const int tid = threadIdx.x;
  if (tid < 64) {
    int v = (tid < NB && tid < (int)blockIdx.x) ? partial[tid] : 0;
    #pragma unroll
    for (int off = 1; off < 64; off <<= 1) v += __shfl_xor(v, off, 64);
    if (tid == 0) s_off = v;
  }
  __syncthreads();
  const int off = s_off;
  const int base = blockIdx.x * 1024 + tid * 4;
  if (base + 3 < N) {
    int4 v = *reinterpret_cast<const int4*>(&excl[base]);
    v.x += off; v.y += off; v.z += off; v.w += off;
    *reinterpret_cast<int4*>(&row_ptr[base]) = v;
    *reinterpret_cast<int4*>(&cursor[base]) = v;
  } else {
    for (int j = 0; j < 4; ++j)
      if (base + j < N) { int v = excl[base + j] + off; row_ptr[base + j] = v; cursor[base + j] = v; }
  }
}

// edge word: src (17 bits) << 15 | fp16(w*alpha) >> 1 (15 bits; w*alpha in [0,0.5])
__global__ void reindex_edges(const int* __restrict__ src, const int* __restrict__ dst,
                              const float* __restrict__ w, int* __restrict__ cursor,
                              unsigned* __restrict__ edges, int E) {
  int i = blockIdx.x * blockDim.x + threadIdx.x;
  if (i < E) {
    int d = dst[i];
    int slot = atomicAdd(&cursor[d], 1);
    unsigned hb = __half_as_ushort(__float2half(w[i] * ALPHA));
    edges[slot] = ((unsigned)src[i] << 15) | (hb >> 1);
  }
}

__device__ __forceinline__ float unpack_w(unsigned p) {
  return __half2float(__ushort_as_half((unsigned short)((p & 0x7FFFu) << 1)));
}

// ---------------- aggregate (pull, bf16 support, full-row bursts), fused blend+relu ----------------
__global__ __launch_bounds__(256) void aggregate(
    const unsigned short* __restrict__ support,
    const int* __restrict__ row_ptr, const int* __restrict__ deg,
    const unsigned* __restrict__ edges,
    const float* __restrict__ init, float* __restrict__ out, int N) {
  int node = blockIdx.x * 4 + (threadIdx.x >> 6);
  if (node >= N) return;
  int lane = threadIdx.x & 63;
  int start = row_ptr[node], cnt = deg[node];

  // hoist the streaming init load above the gather loop
  float4 ini = *reinterpret_cast<const float4*>(&init[(size_t)node * 256 + lane * 4]);

  float4 acc = make_float4(0.f, 0.f, 0.f, 0.f);
  int e = 0;
  for (; e + 7 < cnt; e += 8) {  // 8 outstanding contiguous 512B gathers per wave
    unsigned p[8];
    #pragma unroll
    for (int j = 0; j < 8; ++j) p[j] = edges[start + e + j];
    ushort4 v[8];
    #pragma unroll
    for (int j = 0; j < 8; ++j)
      v[j] = *reinterpret_cast<const ushort4*>(&support[(size_t)(p[j] >> 15) * 256 + lane * 4]);
    #pragma unroll
    for (int j = 0; j < 8; ++j) {
      float wj = unpack_w(p[j]);
      acc.x += wj * bf2f(v[j].x);
      acc.y += wj * bf2f(v[j].y);
      acc.z += wj * bf2f(v[j].z);
      acc.w += wj * bf2f(v[j].w);
    }
  }
  for (; e < cnt; ++e) {
    unsigned p = edges[start + e];
    ushort4 v = *reinterpret_cast<const ushort4*>(&support[(size_t)(p >> 15) * 256 + lane * 4]);
    float wj = unpack_w(p);
    acc.x += wj * bf2f(v.x); acc.y += wj * bf2f(v.y);
    acc.z += wj * bf2f(v.z); acc.w += wj * bf2f(v.w);
  }
  float4 o;
  o.x = fmaxf(acc.x + (1.f - ALPHA) * ini.x, 0.f);
  o.y = fmaxf(acc.y + (1.f - ALPHA) * ini.y, 0.f);
  o.z = fmaxf(acc.z + (1.f - ALPHA) * ini.z, 0.f);
  o.w = fmaxf(acc.w + (1.f - ALPHA) * ini.w, 0.f);
  *reinterpret_cast<float4*>(&out[(size_t)node * 256 + lane * 4]) = o;
}

extern "C" void kernel_launch(void* const* d_in, const int* in_sizes, int n_in,
                              void* d_out, int out_size, void* d_ws, size_t ws_size,
                              hipStream_t stream) {
  const float* input   = (const float*)d_in[0];
  const int*   adj_src = (const int*)d_in[1];
  const int*   adj_dst = (const int*)d_in[2];
  const float* adj_w   = (const float*)d_in[3];
  const float* init_in = (const float*)d_in[4];
  const float* weight  = (const float*)d_in[5];
  float* out = (float*)d_out;

  const int N = in_sizes[0] / 256;  // 50000
  const int E = in_sizes[1];        // 800000

  char* ws = (char*)d_ws;
  unsigned short* support = (unsigned short*)ws; ws += (size_t)N * 256 * 2;  // 25.6 MB
  unsigned short* Ab      = (unsigned short*)ws; ws += (size_t)N * 256 * 2;  // 25.6 MB
  unsigned short* Wt      = (unsigned short*)ws; ws += 256 * 256 * 2;
  int* deg     = (int*)ws; ws += (size_t)N * 4;
  int* row_ptr = (int*)ws; ws += (size_t)N * 4;
  int* cursor  = (int*)ws; ws += (size_t)N * 4;
  int* excl    = (int*)ws; ws += (size_t)N * 4;
  int* partial = (int*)ws; ws += 256;
  unsigned* edges = (unsigned*)ws; ws += (size_t)E * 4;

  const int NB = (N + 1023) / 1024;  // 49 (<= 64 required by scan_pass2)

  transpose_w<<<dim3(16, 16), dim3(16, 16), 0, stream>>>(weight, Wt);
  cvt_input<<<2048, 256, 0, stream>>>(input, Ab, N * 256 / 8);
  gemm_mfma<<<dim3((N + 127) / 128), 256, 0, stream>>>(Ab, Wt, support, N);

  hipMemsetAsync(deg, 0, (size_t)N * 4, stream);
  histogram_dst<<<(E + 255) / 256, 256, 0, stream>>>(adj_dst, deg, E);
  scan_pass1<<<NB, 256, 0, stream>>>(deg, excl, partial, N);
  scan_pass2<<<NB, 256, 0, stream>>>(excl, partial, row_ptr, cursor, N, NB);
  reindex_edges<<<(E + 255) / 256, 256, 0, stream>>>(adj_src, adj_dst, adj_w, cursor, edges, E);

  aggregate<<<(N + 3) / 4, 256, 0, stream>>>(support, row_ptr, deg, edges, init_in, out, N);
}